// Round 1
// baseline (361.955 us; speedup 1.0000x reference)
//
#include <hip/hip_runtime.h>
#include <hip/hip_bf16.h>

typedef __attribute__((ext_vector_type(8))) short short8;
typedef __attribute__((ext_vector_type(4))) float floatx4;

__device__ inline unsigned short f2bf(float f) {
    unsigned u = __float_as_uint(f);
    u += 0x7fffu + ((u >> 16) & 1u);   // round-to-nearest-even
    return (unsigned short)(u >> 16);
}

// ---------------- prep kernels ----------------

__global__ void prep_weights(const float* __restrict__ w_in, const float* __restrict__ w1s,
                             const float* __restrict__ w1n, const float* __restrict__ w2s,
                             const float* __restrict__ w2n,
                             const float* __restrict__ b_in, const float* __restrict__ b1s,
                             const float* __restrict__ b1n, const float* __restrict__ b2s,
                             const float* __restrict__ b2n,
                             unsigned short* __restrict__ wb, float* __restrict__ biasf) {
    int idx = blockIdx.x * 256 + threadIdx.x;
    if (idx < 5 * 16384) {
        int m = idx >> 14, j = idx & 16383;
        const float* src = (m == 0) ? w_in : (m == 1) ? w1s : (m == 2) ? w1n : (m == 3) ? w2s : w2n;
        wb[idx] = f2bf(src[j]);
    }
    if (idx < 128) {
        biasf[idx]       = b_in[idx];
        biasf[128 + idx] = b1s[idx] + b1n[idx];
        biasf[256 + idx] = b2s[idx] + b2n[idx];
    }
}

__global__ void build_x0(const float* __restrict__ attr, const float* __restrict__ cc,
                         const float* __restrict__ bl, const float* __restrict__ ex,
                         unsigned short* __restrict__ x0, int N, int ATTR) {
    int idx = blockIdx.x * 256 + threadIdx.x;
    if (idx >= N * 128) return;
    int row = idx >> 7, col = idx & 127;
    float v;
    if (col < ATTR)            v = attr[row * ATTR + col];
    else if (col == ATTR)      v = cc[row];
    else if (col == ATTR + 1)  v = bl[row];
    else                       v = ex[row];
    x0[idx] = f2bf(v);
}

// ---------------- CSR build ----------------

__global__ void deg_count(const int* __restrict__ e, int* __restrict__ deg, int E) {
    int i = blockIdx.x * 256 + threadIdx.x;
    if (i < E) atomicAdd(&deg[e[E + i]], 1);
}

__global__ void scan_block(const int* __restrict__ in, int* __restrict__ outs,
                           int* __restrict__ part) {
    __shared__ int s[256];
    int tid = threadIdx.x;
    int i = blockIdx.x * 256 + tid;
    int v = in[i];
    s[tid] = v;
    __syncthreads();
    for (int o = 1; o < 256; o <<= 1) {
        int t = (tid >= o) ? s[tid - o] : 0;
        __syncthreads();
        s[tid] += t;
        __syncthreads();
    }
    outs[i] = s[tid] - v;   // exclusive
    if (tid == 255) part[blockIdx.x] = s[255];
}

__global__ void scan_top(const int* __restrict__ part, int* __restrict__ boff, int nb) {
    __shared__ int s[256];
    int tid = threadIdx.x;
    int v = (tid < nb) ? part[tid] : 0;
    s[tid] = v;
    __syncthreads();
    for (int o = 1; o < 256; o <<= 1) {
        int t = (tid >= o) ? s[tid - o] : 0;
        __syncthreads();
        s[tid] += t;
        __syncthreads();
    }
    boff[tid] = s[tid] - v;
}

__global__ void scan_add(const int* __restrict__ tmps, const int* __restrict__ boff,
                         int* __restrict__ rows, int* __restrict__ curs, int N) {
    int i = blockIdx.x * 256 + threadIdx.x;
    if (i > N) return;
    int v = tmps[i] + boff[i >> 8];
    rows[i] = v;
    if (i < N) curs[i] = v;
}

__global__ void scatter_edges(const int* __restrict__ e, int* __restrict__ curs,
                              int* __restrict__ colv, int E) {
    int i = blockIdx.x * 256 + threadIdx.x;
    if (i < E) {
        int t = e[E + i];
        int p = atomicAdd(&curs[t], 1);
        colv[p] = e[i];
    }
}

// ---------------- segment mean (gather, one wave per node) ----------------

__global__ __launch_bounds__(256) void agg_mean(const unsigned short* __restrict__ x,
                                                const int* __restrict__ rows,
                                                const int* __restrict__ colv,
                                                unsigned short* __restrict__ nm, int N) {
    int wid = (blockIdx.x * 256 + threadIdx.x) >> 6;
    int lane = threadIdx.x & 63;
    if (wid >= N) return;
    int s0 = rows[wid], s1 = rows[wid + 1];
    float a0 = 0.f, a1 = 0.f;
    int e = s0;
    for (; e + 1 < s1; e += 2) {
        int sA = colv[e], sB = colv[e + 1];
        unsigned va = *(const unsigned*)(x + (size_t)sA * 128 + lane * 2);
        unsigned vb = *(const unsigned*)(x + (size_t)sB * 128 + lane * 2);
        a0 += __uint_as_float(va << 16) + __uint_as_float(vb << 16);
        a1 += __uint_as_float(va & 0xffff0000u) + __uint_as_float(vb & 0xffff0000u);
    }
    if (e < s1) {
        int sA = colv[e];
        unsigned va = *(const unsigned*)(x + (size_t)sA * 128 + lane * 2);
        a0 += __uint_as_float(va << 16);
        a1 += __uint_as_float(va & 0xffff0000u);
    }
    int deg = s1 - s0;
    float inv = 1.0f / (float)(deg > 1 ? deg : 1);
    a0 *= inv;
    a1 *= inv;
    unsigned outp = ((unsigned)f2bf(a1) << 16) | (unsigned)f2bf(a0);
    *(unsigned*)(nm + (size_t)wid * 128 + lane * 2) = outp;
}

// ---------------- fused GEMM: out = act(X0*W0^T + [X1*W1^T] + bias) [*exist] ----------------
// Block: 64 nodes x 128 outputs; 4 waves, each 64x32 via 16x16x32 bf16 MFMA.
// LDS rows padded to 136 bf16 (272 B) -> conflict-free ds_read_b128.

__global__ __launch_bounds__(256, 3) void gemm_fused(
    const unsigned short* __restrict__ X0, const unsigned short* __restrict__ X1,
    const unsigned short* __restrict__ W0, const unsigned short* __restrict__ W1,
    const float* __restrict__ bias, const float* __restrict__ ex,
    unsigned short* __restrict__ obf, float* __restrict__ of32,
    int N, int relu, int nphase) {
    __shared__ unsigned short lx[64 * 136];
    __shared__ unsigned short lw[128 * 136];
    int tid = threadIdx.x;
    int lane = tid & 63;
    int w = tid >> 6;
    int node0 = blockIdx.x * 64;
    int n_off = w * 32;
    int q = lane >> 4;      // quad 0..3
    int m16 = lane & 15;

    floatx4 acc[4][2];
    for (int nt = 0; nt < 2; ++nt) {
        float bv = bias[n_off + nt * 16 + m16];
        floatx4 b4 = {bv, bv, bv, bv};
        for (int mt = 0; mt < 4; ++mt) acc[mt][nt] = b4;
    }

    for (int ph = 0; ph < nphase; ++ph) {
        const unsigned short* X = ph ? X1 : X0;
        const unsigned short* W = ph ? W1 : W0;
        // stage X tile (64 x 128)
        for (int i = 0; i < 4; ++i) {
            int c = tid + 256 * i;          // 16B chunk id, 0..1023
            int nd = c >> 4, ck = c & 15;
            short8 v = {0, 0, 0, 0, 0, 0, 0, 0};
            if (node0 + nd < N) v = *(const short8*)(X + (size_t)(node0 + nd) * 128 + ck * 8);
            *(short8*)(lx + nd * 136 + ck * 8) = v;
        }
        // stage W (128 x 128)
        for (int i = 0; i < 8; ++i) {
            int c = tid + 256 * i;          // 0..2047
            int rw = c >> 4, ck = c & 15;
            *(short8*)(lw + rw * 136 + ck * 8) = *(const short8*)(W + rw * 128 + ck * 8);
        }
        __syncthreads();
        for (int kk = 0; kk < 4; ++kk) {
            short8 a[4], b[2];
            for (int mt = 0; mt < 4; ++mt)
                a[mt] = *(const short8*)(lx + (mt * 16 + m16) * 136 + kk * 32 + q * 8);
            for (int nt = 0; nt < 2; ++nt)
                b[nt] = *(const short8*)(lw + (n_off + nt * 16 + m16) * 136 + kk * 32 + q * 8);
            for (int mt = 0; mt < 4; ++mt)
                for (int nt = 0; nt < 2; ++nt)
                    acc[mt][nt] = __builtin_amdgcn_mfma_f32_16x16x32_bf16(a[mt], b[nt], acc[mt][nt], 0, 0, 0);
        }
        __syncthreads();
    }

    // epilogue: C layout col = lane&15, row = q*4 + r
    for (int mt = 0; mt < 4; ++mt) {
        int rbase = node0 + mt * 16 + q * 4;
        for (int r = 0; r < 4; ++r) {
            int rr = rbase + r;
            if (rr >= N) continue;
            float e = ex ? ex[rr] : 1.0f;
            for (int nt = 0; nt < 2; ++nt) {
                float v = acc[mt][nt][r];
                if (relu) v = fmaxf(v, 0.0f);
                v *= e;
                int col = n_off + nt * 16 + m16;
                if (obf) obf[(size_t)rr * 128 + col] = f2bf(v);
                else     of32[(size_t)rr * 128 + col] = v;
            }
        }
    }
}

// ---------------- launch ----------------

extern "C" void kernel_launch(void* const* d_in, const int* in_sizes, int n_in,
                              void* d_out, int out_size, void* d_ws, size_t ws_size,
                              hipStream_t stream) {
    const float* attr = (const float*)d_in[0];
    const float* cc   = (const float*)d_in[1];
    const float* bl   = (const float*)d_in[2];
    const float* ex   = (const float*)d_in[3];
    const float* w_in = (const float*)d_in[4];
    const float* b_in = (const float*)d_in[5];
    const float* w1s  = (const float*)d_in[6];
    const float* b1s  = (const float*)d_in[7];
    const float* w1n  = (const float*)d_in[8];
    const float* b1n  = (const float*)d_in[9];
    const float* w2s  = (const float*)d_in[10];
    const float* b2s  = (const float*)d_in[11];
    const float* w2n  = (const float*)d_in[12];
    const float* b2n  = (const float*)d_in[13];
    const int*   eidx = (const int*)d_in[14];

    int N = in_sizes[3];
    int ATTR = in_sizes[0] / N;
    int E = in_sizes[14] / 2;
    int Npad = ((N + 63) / 64) * 64;
    int SCAN_N = ((N + 1 + 255) / 256) * 256;   // requires N <= 65535 (holds: 50000)
    int nscan = SCAN_N / 256;

    char* ws = (char*)d_ws;
    size_t off = 0;
    auto alloc = [&](size_t bytes) -> char* {
        off = (off + 255) & ~(size_t)255;
        char* p = ws + off;
        off += bytes;
        return p;
    };
    unsigned short* xa = (unsigned short*)alloc((size_t)Npad * 128 * 2);  // x0, later x2
    unsigned short* xb = (unsigned short*)alloc((size_t)Npad * 128 * 2);  // x1
    unsigned short* xc = (unsigned short*)alloc((size_t)Npad * 128 * 2);  // nm1, later nm2
    int* colv = (int*)alloc((size_t)E * 4);
    int* deg  = (int*)alloc((size_t)SCAN_N * 4);
    int* tmps = (int*)alloc((size_t)SCAN_N * 4);
    int* rows = (int*)alloc((size_t)(SCAN_N + 1) * 4);
    int* curs = (int*)alloc((size_t)SCAN_N * 4);
    int* part = (int*)alloc(256 * 4);
    int* boff = (int*)alloc(256 * 4);
    unsigned short* wb = (unsigned short*)alloc((size_t)5 * 16384 * 2);
    float* biasf = (float*)alloc(3 * 128 * 4);

    hipMemsetAsync(deg, 0, (size_t)SCAN_N * 4, stream);

    prep_weights<<<(5 * 16384 + 255) / 256, 256, 0, stream>>>(
        w_in, w1s, w1n, w2s, w2n, b_in, b1s, b1n, b2s, b2n, wb, biasf);
    build_x0<<<(N * 128 + 255) / 256, 256, 0, stream>>>(attr, cc, bl, ex, xa, N, ATTR);
    deg_count<<<(E + 255) / 256, 256, 0, stream>>>(eidx, deg, E);
    scan_block<<<nscan, 256, 0, stream>>>(deg, tmps, part);
    scan_top<<<1, 256, 0, stream>>>(part, boff, nscan);
    scan_add<<<(N + 1 + 255) / 256, 256, 0, stream>>>(tmps, boff, rows, curs, N);
    scatter_edges<<<(E + 255) / 256, 256, 0, stream>>>(eidx, curs, colv, E);

    int gblk = Npad / 64;
    // layer 0: x1 = relu(x0 @ W_in^T + b_in)
    gemm_fused<<<gblk, 256, 0, stream>>>(xa, (const unsigned short*)nullptr,
                                         wb, (const unsigned short*)nullptr,
                                         biasf, (const float*)nullptr,
                                         xb, (float*)nullptr, N, 1, 1);
    // nm1 = segment_mean(x1)
    agg_mean<<<(N + 3) / 4, 256, 0, stream>>>(xb, rows, colv, xc, N);
    // layer 1: x2 = relu(x1 @ W1s^T + nm1 @ W1n^T + b1s + b1n) * exist
    gemm_fused<<<gblk, 256, 0, stream>>>(xb, xc, wb + 16384, wb + 2 * 16384,
                                         biasf + 128, ex, xa, (float*)nullptr, N, 1, 2);
    // nm2 = segment_mean(x2)
    agg_mean<<<(N + 3) / 4, 256, 0, stream>>>(xa, rows, colv, xc, N);
    // layer 2: out = (x2 @ W2s^T + nm2 @ W2n^T + b2s + b2n) * exist   (fp32 out)
    gemm_fused<<<gblk, 256, 0, stream>>>(xa, xc, wb + 3 * 16384, wb + 4 * 16384,
                                         biasf + 256, ex, (unsigned short*)nullptr,
                                         (float*)d_out, N, 0, 2);
}

// Round 2
// 310.245 us; speedup vs baseline: 1.1667x; 1.1667x over previous
//
#include <hip/hip_runtime.h>
#include <hip/hip_bf16.h>

typedef __attribute__((ext_vector_type(8))) short short8;
typedef __attribute__((ext_vector_type(4))) float floatx4;

__device__ inline unsigned short f2bf(float f) {
    unsigned u = __float_as_uint(f);
    u += 0x7fffu + ((u >> 16) & 1u);   // round-to-nearest-even
    return (unsigned short)(u >> 16);
}

// ---------------- prep kernels ----------------

__global__ void prep_weights(const float* __restrict__ w_in, const float* __restrict__ w1s,
                             const float* __restrict__ w1n, const float* __restrict__ w2s,
                             const float* __restrict__ w2n,
                             const float* __restrict__ b_in, const float* __restrict__ b1s,
                             const float* __restrict__ b1n, const float* __restrict__ b2s,
                             const float* __restrict__ b2n,
                             unsigned short* __restrict__ wb, float* __restrict__ biasf) {
    int idx = blockIdx.x * 256 + threadIdx.x;
    if (idx < 5 * 16384) {
        int m = idx >> 14, j = idx & 16383;
        const float* src = (m == 0) ? w_in : (m == 1) ? w1s : (m == 2) ? w1n : (m == 3) ? w2s : w2n;
        wb[idx] = f2bf(src[j]);
    }
    if (idx < 128) {
        biasf[idx]       = b_in[idx];
        biasf[128 + idx] = b1s[idx] + b1n[idx];
        biasf[256 + idx] = b2s[idx] + b2n[idx];
    }
}

__global__ void build_x0(const float* __restrict__ attr, const float* __restrict__ cc,
                         const float* __restrict__ bl, const float* __restrict__ ex,
                         unsigned short* __restrict__ x0, int N, int ATTR) {
    int idx = blockIdx.x * 256 + threadIdx.x;
    if (idx >= N * 128) return;
    int row = idx >> 7, col = idx & 127;
    float v;
    if (col < ATTR)            v = attr[row * ATTR + col];
    else if (col == ATTR)      v = cc[row];
    else if (col == ATTR + 1)  v = bl[row];
    else                       v = ex[row];
    x0[idx] = f2bf(v);
}

// ---------------- CSR build: binned counting sort (coalesced writes) ----------------
// chunk = 512 consecutive target nodes; NCHUNK <= 128.
// packed edge word: (chunk<<25) | (src<<9) | (tgt&511)   [requires src < 65536]

__global__ __launch_bounds__(256) void chunk_hist(const int* __restrict__ e,
                                                  int* __restrict__ chunk_count, int E) {
    __shared__ int h[128];
    if (threadIdx.x < 128) h[threadIdx.x] = 0;
    __syncthreads();
    for (int i = blockIdx.x * 256 + threadIdx.x; i < E; i += gridDim.x * 256)
        atomicAdd(&h[e[E + i] >> 9], 1);
    __syncthreads();
    if (threadIdx.x < 128 && h[threadIdx.x])
        atomicAdd(&chunk_count[threadIdx.x], h[threadIdx.x]);
}

__global__ void chunk_scan(const int* __restrict__ chunk_count,
                           int* __restrict__ chunk_base, int* __restrict__ chunk_cursor) {
    __shared__ int s[128];
    int t = threadIdx.x;
    int v = chunk_count[t];
    s[t] = v;
    __syncthreads();
    for (int o = 1; o < 128; o <<= 1) {
        int u = (t >= o) ? s[t - o] : 0;
        __syncthreads();
        s[t] += u;
        __syncthreads();
    }
    int excl = s[t] - v;
    chunk_base[t] = excl;
    chunk_cursor[t] = excl;
}

#define BTILE 4096

__global__ __launch_bounds__(256) void bin_pass(const int* __restrict__ e,
                                                int* __restrict__ chunk_cursor,
                                                unsigned* __restrict__ packed_out,
                                                int E, int ntiles) {
    __shared__ unsigned buf[BTILE];
    __shared__ unsigned sbuf[BTILE];
    __shared__ int hist[128], offs[128], gbase[128], lcur[128];
    int t = threadIdx.x;
    for (int tile = blockIdx.x; tile < ntiles; tile += gridDim.x) {
        int e0 = tile * BTILE;
        int cnt = min(BTILE, E - e0);
        if (t < 128) hist[t] = 0;
        __syncthreads();
        for (int j = t; j < cnt; j += 256) {
            unsigned src = (unsigned)e[e0 + j];
            unsigned tgt = (unsigned)e[E + e0 + j];
            unsigned c = tgt >> 9;
            buf[j] = (c << 25) | (src << 9) | (tgt & 511u);
            atomicAdd(&hist[c], 1);
        }
        __syncthreads();
        // exclusive scan over 128 buckets
        if (t < 128) offs[t] = hist[t];
        __syncthreads();
        for (int o = 1; o < 128; o <<= 1) {
            int v = (t < 128 && t >= o) ? offs[t - o] : 0;
            __syncthreads();
            if (t < 128) offs[t] += v;
            __syncthreads();
        }
        if (t < 128) {
            int excl = offs[t] - hist[t];
            offs[t] = excl;
            lcur[t] = excl;
            gbase[t] = (hist[t] > 0) ? atomicAdd(&chunk_cursor[t], hist[t]) : 0;
        }
        __syncthreads();
        // LDS sort by chunk
        for (int j = t; j < cnt; j += 256) {
            unsigned v = buf[j];
            int c = v >> 25;
            int p = atomicAdd(&lcur[c], 1);
            sbuf[p] = v;
        }
        __syncthreads();
        // coalesced run copy: wave w handles buckets w, w+4, ...
        int wv = t >> 6, lane = t & 63;
        for (int c = wv; c < 128; c += 4) {
            int n = hist[c], lo = offs[c], gb = gbase[c];
            for (int j = lane; j < n; j += 64)
                packed_out[gb + j] = sbuf[lo + j];
        }
        __syncthreads();
    }
}

#define CSR_CAP 12288

__global__ __launch_bounds__(256) void chunk_csr(const unsigned* __restrict__ packed,
                                                 const int* __restrict__ chunk_base,
                                                 const int* __restrict__ chunk_cursor,
                                                 int* __restrict__ rows, int* __restrict__ colv,
                                                 int N) {
    __shared__ int hist[512], offs[512], lcnt[512], pp[256];
    __shared__ int sbuf[CSR_CAP];
    int c = blockIdx.x;
    int base = chunk_base[c];
    int cnt = chunk_cursor[c] - base;
    int t = threadIdx.x;
    hist[t] = 0;
    hist[t + 256] = 0;
    __syncthreads();
    for (int j = t; j < cnt; j += 256)
        atomicAdd(&hist[packed[base + j] & 511u], 1);
    __syncthreads();
    // exclusive scan over 512 via pair-reduce + 256-scan
    int a0 = hist[2 * t], a1 = hist[2 * t + 1];
    pp[t] = a0 + a1;
    __syncthreads();
    for (int o = 1; o < 256; o <<= 1) {
        int v = (t >= o) ? pp[t - o] : 0;
        __syncthreads();
        pp[t] += v;
        __syncthreads();
    }
    int excl = pp[t] - (a0 + a1);
    offs[2 * t] = excl;
    offs[2 * t + 1] = excl + a0;
    lcnt[2 * t] = 0;
    lcnt[2 * t + 1] = 0;
    __syncthreads();
    // rows[] (global CSR offsets); node == N gets base+cnt == E
    for (int j = t; j < 512; j += 256) {
        int node = c * 512 + j;
        if (node <= N) rows[node] = base + offs[j];
    }
    if (cnt <= CSR_CAP) {
        for (int j = t; j < cnt; j += 256) {
            unsigned v = packed[base + j];
            int node = v & 511u;
            int p = offs[node] + atomicAdd(&lcnt[node], 1);
            sbuf[p] = (v >> 9) & 0xFFFFu;
        }
        __syncthreads();
        for (int j = t; j < cnt; j += 256) colv[base + j] = sbuf[j];
    } else {
        // fallback (shouldn't trigger for uniform-random edges)
        for (int j = t; j < cnt; j += 256) {
            unsigned v = packed[base + j];
            int node = v & 511u;
            int p = offs[node] + atomicAdd(&lcnt[node], 1);
            colv[base + p] = (v >> 9) & 0xFFFFu;
        }
    }
}

// ---------------- segment mean (gather, one wave per node) ----------------

__global__ __launch_bounds__(256) void agg_mean(const unsigned short* __restrict__ x,
                                                const int* __restrict__ rows,
                                                const int* __restrict__ colv,
                                                unsigned short* __restrict__ nm, int N) {
    int wid = (blockIdx.x * 256 + threadIdx.x) >> 6;
    int lane = threadIdx.x & 63;
    if (wid >= N) return;
    int s0 = rows[wid], s1 = rows[wid + 1];
    float a0 = 0.f, a1 = 0.f;
    int e = s0;
    for (; e + 1 < s1; e += 2) {
        int sA = colv[e], sB = colv[e + 1];
        unsigned va = *(const unsigned*)(x + (size_t)sA * 128 + lane * 2);
        unsigned vb = *(const unsigned*)(x + (size_t)sB * 128 + lane * 2);
        a0 += __uint_as_float(va << 16) + __uint_as_float(vb << 16);
        a1 += __uint_as_float(va & 0xffff0000u) + __uint_as_float(vb & 0xffff0000u);
    }
    if (e < s1) {
        int sA = colv[e];
        unsigned va = *(const unsigned*)(x + (size_t)sA * 128 + lane * 2);
        a0 += __uint_as_float(va << 16);
        a1 += __uint_as_float(va & 0xffff0000u);
    }
    int deg = s1 - s0;
    float inv = 1.0f / (float)(deg > 1 ? deg : 1);
    a0 *= inv;
    a1 *= inv;
    unsigned outp = ((unsigned)f2bf(a1) << 16) | (unsigned)f2bf(a0);
    *(unsigned*)(nm + (size_t)wid * 128 + lane * 2) = outp;
}

// ---------------- fused GEMM: out = act(X0*W0^T + [X1*W1^T] + bias) [*exist] ----------------
// Block: 64 nodes x 128 outputs; 4 waves, each 64x32 via 16x16x32 bf16 MFMA.
// LDS rows padded to 136 bf16 (272 B) -> conflict-free ds_read_b128.

__global__ __launch_bounds__(256, 3) void gemm_fused(
    const unsigned short* __restrict__ X0, const unsigned short* __restrict__ X1,
    const unsigned short* __restrict__ W0, const unsigned short* __restrict__ W1,
    const float* __restrict__ bias, const float* __restrict__ ex,
    unsigned short* __restrict__ obf, float* __restrict__ of32,
    int N, int relu, int nphase) {
    __shared__ unsigned short lx[64 * 136];
    __shared__ unsigned short lw[128 * 136];
    int tid = threadIdx.x;
    int lane = tid & 63;
    int w = tid >> 6;
    int node0 = blockIdx.x * 64;
    int n_off = w * 32;
    int q = lane >> 4;      // quad 0..3
    int m16 = lane & 15;

    floatx4 acc[4][2];
    for (int nt = 0; nt < 2; ++nt) {
        float bv = bias[n_off + nt * 16 + m16];
        floatx4 b4 = {bv, bv, bv, bv};
        for (int mt = 0; mt < 4; ++mt) acc[mt][nt] = b4;
    }

    for (int ph = 0; ph < nphase; ++ph) {
        const unsigned short* X = ph ? X1 : X0;
        const unsigned short* W = ph ? W1 : W0;
        // stage X tile (64 x 128)
        for (int i = 0; i < 4; ++i) {
            int c = tid + 256 * i;          // 16B chunk id, 0..1023
            int nd = c >> 4, ck = c & 15;
            short8 v = {0, 0, 0, 0, 0, 0, 0, 0};
            if (node0 + nd < N) v = *(const short8*)(X + (size_t)(node0 + nd) * 128 + ck * 8);
            *(short8*)(lx + nd * 136 + ck * 8) = v;
        }
        // stage W (128 x 128)
        for (int i = 0; i < 8; ++i) {
            int c = tid + 256 * i;          // 0..2047
            int rw = c >> 4, ck = c & 15;
            *(short8*)(lw + rw * 136 + ck * 8) = *(const short8*)(W + rw * 128 + ck * 8);
        }
        __syncthreads();
        for (int kk = 0; kk < 4; ++kk) {
            short8 a[4], b[2];
            for (int mt = 0; mt < 4; ++mt)
                a[mt] = *(const short8*)(lx + (mt * 16 + m16) * 136 + kk * 32 + q * 8);
            for (int nt = 0; nt < 2; ++nt)
                b[nt] = *(const short8*)(lw + (n_off + nt * 16 + m16) * 136 + kk * 32 + q * 8);
            for (int mt = 0; mt < 4; ++mt)
                for (int nt = 0; nt < 2; ++nt)
                    acc[mt][nt] = __builtin_amdgcn_mfma_f32_16x16x32_bf16(a[mt], b[nt], acc[mt][nt], 0, 0, 0);
        }
        __syncthreads();
    }

    // epilogue: C layout col = lane&15, row = q*4 + r
    for (int mt = 0; mt < 4; ++mt) {
        int rbase = node0 + mt * 16 + q * 4;
        for (int r = 0; r < 4; ++r) {
            int rr = rbase + r;
            if (rr >= N) continue;
            float e = ex ? ex[rr] : 1.0f;
            for (int nt = 0; nt < 2; ++nt) {
                float v = acc[mt][nt][r];
                if (relu) v = fmaxf(v, 0.0f);
                v *= e;
                int col = n_off + nt * 16 + m16;
                if (obf) obf[(size_t)rr * 128 + col] = f2bf(v);
                else     of32[(size_t)rr * 128 + col] = v;
            }
        }
    }
}

// ---------------- launch ----------------

extern "C" void kernel_launch(void* const* d_in, const int* in_sizes, int n_in,
                              void* d_out, int out_size, void* d_ws, size_t ws_size,
                              hipStream_t stream) {
    const float* attr = (const float*)d_in[0];
    const float* cc   = (const float*)d_in[1];
    const float* bl   = (const float*)d_in[2];
    const float* ex   = (const float*)d_in[3];
    const float* w_in = (const float*)d_in[4];
    const float* b_in = (const float*)d_in[5];
    const float* w1s  = (const float*)d_in[6];
    const float* b1s  = (const float*)d_in[7];
    const float* w1n  = (const float*)d_in[8];
    const float* b1n  = (const float*)d_in[9];
    const float* w2s  = (const float*)d_in[10];
    const float* b2s  = (const float*)d_in[11];
    const float* w2n  = (const float*)d_in[12];
    const float* b2n  = (const float*)d_in[13];
    const int*   eidx = (const int*)d_in[14];

    int N = in_sizes[3];
    int ATTR = in_sizes[0] / N;
    int E = in_sizes[14] / 2;
    int Npad = ((N + 63) / 64) * 64;
    int nchunk = (N >> 9) + 1;              // node N (for rows[N]) lives in chunk N>>9
    int ntiles = (E + BTILE - 1) / BTILE;

    char* ws = (char*)d_ws;
    size_t off = 0;
    auto alloc = [&](size_t bytes) -> char* {
        off = (off + 255) & ~(size_t)255;
        char* p = ws + off;
        off += bytes;
        return p;
    };
    unsigned short* xa = (unsigned short*)alloc((size_t)Npad * 128 * 2);  // x0, later x2
    unsigned short* xb = (unsigned short*)alloc((size_t)Npad * 128 * 2);  // x1
    unsigned short* xc = (unsigned short*)alloc((size_t)Npad * 128 * 2);  // nm1, later nm2
    int* colv = (int*)alloc((size_t)E * 4);
    unsigned* packed = (unsigned*)alloc((size_t)E * 4);
    int* rows = (int*)alloc((size_t)(N + 256) * 4);
    int* chunk_count  = (int*)alloc(128 * 4);
    int* chunk_base   = (int*)alloc(128 * 4);
    int* chunk_cursor = (int*)alloc(128 * 4);
    unsigned short* wb = (unsigned short*)alloc((size_t)5 * 16384 * 2);
    float* biasf = (float*)alloc(3 * 128 * 4);

    hipMemsetAsync(chunk_count, 0, 128 * 4, stream);

    prep_weights<<<(5 * 16384 + 255) / 256, 256, 0, stream>>>(
        w_in, w1s, w1n, w2s, w2n, b_in, b1s, b1n, b2s, b2n, wb, biasf);
    build_x0<<<(N * 128 + 255) / 256, 256, 0, stream>>>(attr, cc, bl, ex, xa, N, ATTR);

    chunk_hist<<<256, 256, 0, stream>>>(eidx, chunk_count, E);
    chunk_scan<<<1, 128, 0, stream>>>(chunk_count, chunk_base, chunk_cursor);
    bin_pass<<<(ntiles < 256 ? ntiles : 256), 256, 0, stream>>>(eidx, chunk_cursor, packed, E, ntiles);
    chunk_csr<<<nchunk, 256, 0, stream>>>(packed, chunk_base, chunk_cursor, rows, colv, N);

    int gblk = Npad / 64;
    // layer 0: x1 = relu(x0 @ W_in^T + b_in)
    gemm_fused<<<gblk, 256, 0, stream>>>(xa, (const unsigned short*)nullptr,
                                         wb, (const unsigned short*)nullptr,
                                         biasf, (const float*)nullptr,
                                         xb, (float*)nullptr, N, 1, 1);
    // nm1 = segment_mean(x1)
    agg_mean<<<(N + 3) / 4, 256, 0, stream>>>(xb, rows, colv, xc, N);
    // layer 1: x2 = relu(x1 @ W1s^T + nm1 @ W1n^T + b1s + b1n) * exist
    gemm_fused<<<gblk, 256, 0, stream>>>(xb, xc, wb + 16384, wb + 2 * 16384,
                                         biasf + 128, ex, xa, (float*)nullptr, N, 1, 2);
    // nm2 = segment_mean(x2)
    agg_mean<<<(N + 3) / 4, 256, 0, stream>>>(xa, rows, colv, xc, N);
    // layer 2: out = (x2 @ W2s^T + nm2 @ W2n^T + b2s + b2n) * exist   (fp32 out)
    gemm_fused<<<gblk, 256, 0, stream>>>(xa, xc, wb + 3 * 16384, wb + 4 * 16384,
                                         biasf + 256, ex, (unsigned short*)nullptr,
                                         (float*)d_out, N, 0, 2);
}

// Round 3
// 268.022 us; speedup vs baseline: 1.3505x; 1.1575x over previous
//
#include <hip/hip_runtime.h>
#include <hip/hip_bf16.h>

typedef __attribute__((ext_vector_type(8))) short short8;
typedef __attribute__((ext_vector_type(4))) float floatx4;

__device__ inline unsigned short f2bf(float f) {
    unsigned u = __float_as_uint(f);
    u += 0x7fffu + ((u >> 16) & 1u);   // round-to-nearest-even
    return (unsigned short)(u >> 16);
}

// ---------------- prep kernels ----------------

__global__ void prep_weights(const float* __restrict__ w_in, const float* __restrict__ w1s,
                             const float* __restrict__ w1n, const float* __restrict__ w2s,
                             const float* __restrict__ w2n,
                             const float* __restrict__ b_in, const float* __restrict__ b1s,
                             const float* __restrict__ b1n, const float* __restrict__ b2s,
                             const float* __restrict__ b2n,
                             unsigned short* __restrict__ wb, float* __restrict__ biasf) {
    int idx = blockIdx.x * 256 + threadIdx.x;
    if (idx < 5 * 16384) {
        int m = idx >> 14, j = idx & 16383;
        const float* src = (m == 0) ? w_in : (m == 1) ? w1s : (m == 2) ? w1n : (m == 3) ? w2s : w2n;
        wb[idx] = f2bf(src[j]);
    }
    if (idx < 128) {
        biasf[idx]       = b_in[idx];
        biasf[128 + idx] = b1s[idx] + b1n[idx];
        biasf[256 + idx] = b2s[idx] + b2n[idx];
    }
}

__global__ void build_x0(const float* __restrict__ attr, const float* __restrict__ cc,
                         const float* __restrict__ bl, const float* __restrict__ ex,
                         unsigned short* __restrict__ x0, int N, int ATTR) {
    int idx = blockIdx.x * 256 + threadIdx.x;
    if (idx >= N * 128) return;
    int row = idx >> 7, col = idx & 127;
    float v;
    if (col < ATTR)            v = attr[row * ATTR + col];
    else if (col == ATTR)      v = cc[row];
    else if (col == ATTR + 1)  v = bl[row];
    else                       v = ex[row];
    x0[idx] = f2bf(v);
}

// ---------------- CSR build: binned counting sort (coalesced writes) ----------------
// chunk = 512 consecutive target nodes; NCHUNK <= 128.
// packed edge word: (chunk<<25) | (src<<9) | (tgt&511)   [requires src < 65536]

__global__ __launch_bounds__(256) void chunk_hist(const int* __restrict__ e,
                                                  int* __restrict__ chunk_count, int E) {
    __shared__ int h[128];
    if (threadIdx.x < 128) h[threadIdx.x] = 0;
    __syncthreads();
    for (int i = blockIdx.x * 256 + threadIdx.x; i < E; i += gridDim.x * 256)
        atomicAdd(&h[e[E + i] >> 9], 1);
    __syncthreads();
    if (threadIdx.x < 128 && h[threadIdx.x])
        atomicAdd(&chunk_count[threadIdx.x], h[threadIdx.x]);
}

__global__ void chunk_scan(const int* __restrict__ chunk_count,
                           int* __restrict__ chunk_base, int* __restrict__ chunk_cursor) {
    __shared__ int s[128];
    int t = threadIdx.x;
    int v = chunk_count[t];
    s[t] = v;
    __syncthreads();
    for (int o = 1; o < 128; o <<= 1) {
        int u = (t >= o) ? s[t - o] : 0;
        __syncthreads();
        s[t] += u;
        __syncthreads();
    }
    int excl = s[t] - v;
    chunk_base[t] = excl;
    chunk_cursor[t] = excl;
}

#define BTILE 4096

__global__ __launch_bounds__(256) void bin_pass(const int* __restrict__ e,
                                                int* __restrict__ chunk_cursor,
                                                unsigned* __restrict__ packed_out,
                                                int E, int ntiles) {
    __shared__ unsigned buf[BTILE];
    __shared__ unsigned sbuf[BTILE];
    __shared__ int hist[128], offs[128], gbase[128], lcur[128];
    int t = threadIdx.x;
    for (int tile = blockIdx.x; tile < ntiles; tile += gridDim.x) {
        int e0 = tile * BTILE;
        int cnt = min(BTILE, E - e0);
        if (t < 128) hist[t] = 0;
        __syncthreads();
        for (int j = t; j < cnt; j += 256) {
            unsigned src = (unsigned)e[e0 + j];
            unsigned tgt = (unsigned)e[E + e0 + j];
            unsigned c = tgt >> 9;
            buf[j] = (c << 25) | (src << 9) | (tgt & 511u);
            atomicAdd(&hist[c], 1);
        }
        __syncthreads();
        // exclusive scan over 128 buckets
        if (t < 128) offs[t] = hist[t];
        __syncthreads();
        for (int o = 1; o < 128; o <<= 1) {
            int v = (t < 128 && t >= o) ? offs[t - o] : 0;
            __syncthreads();
            if (t < 128) offs[t] += v;
            __syncthreads();
        }
        if (t < 128) {
            int excl = offs[t] - hist[t];
            offs[t] = excl;
            lcur[t] = excl;
            gbase[t] = (hist[t] > 0) ? atomicAdd(&chunk_cursor[t], hist[t]) : 0;
        }
        __syncthreads();
        // LDS sort by chunk
        for (int j = t; j < cnt; j += 256) {
            unsigned v = buf[j];
            int c = v >> 25;
            int p = atomicAdd(&lcur[c], 1);
            sbuf[p] = v;
        }
        __syncthreads();
        // coalesced run copy: wave w handles buckets w, w+4, ...
        int wv = t >> 6, lane = t & 63;
        for (int c = wv; c < 128; c += 4) {
            int n = hist[c], lo = offs[c], gb = gbase[c];
            for (int j = lane; j < n; j += 64)
                packed_out[gb + j] = sbuf[lo + j];
        }
        __syncthreads();
    }
}

#define CSR_CAP 12288

__global__ __launch_bounds__(256) void chunk_csr(const unsigned* __restrict__ packed,
                                                 const int* __restrict__ chunk_base,
                                                 const int* __restrict__ chunk_cursor,
                                                 int* __restrict__ rows, int* __restrict__ colv,
                                                 int N) {
    __shared__ int hist[512], offs[512], lcnt[512], pp[256];
    __shared__ int sbuf[CSR_CAP];
    int c = blockIdx.x;
    int base = chunk_base[c];
    int cnt = chunk_cursor[c] - base;
    int t = threadIdx.x;
    hist[t] = 0;
    hist[t + 256] = 0;
    __syncthreads();
    for (int j = t; j < cnt; j += 256)
        atomicAdd(&hist[packed[base + j] & 511u], 1);
    __syncthreads();
    // exclusive scan over 512 via pair-reduce + 256-scan
    int a0 = hist[2 * t], a1 = hist[2 * t + 1];
    pp[t] = a0 + a1;
    __syncthreads();
    for (int o = 1; o < 256; o <<= 1) {
        int v = (t >= o) ? pp[t - o] : 0;
        __syncthreads();
        pp[t] += v;
        __syncthreads();
    }
    int excl = pp[t] - (a0 + a1);
    offs[2 * t] = excl;
    offs[2 * t + 1] = excl + a0;
    lcnt[2 * t] = 0;
    lcnt[2 * t + 1] = 0;
    __syncthreads();
    // rows[] (global CSR offsets); node == N gets base+cnt == E
    for (int j = t; j < 512; j += 256) {
        int node = c * 512 + j;
        if (node <= N) rows[node] = base + offs[j];
    }
    if (cnt <= CSR_CAP) {
        for (int j = t; j < cnt; j += 256) {
            unsigned v = packed[base + j];
            int node = v & 511u;
            int p = offs[node] + atomicAdd(&lcnt[node], 1);
            sbuf[p] = (v >> 9) & 0xFFFFu;
        }
        __syncthreads();
        for (int j = t; j < cnt; j += 256) colv[base + j] = sbuf[j];
    } else {
        // fallback (shouldn't trigger for uniform-random edges)
        for (int j = t; j < cnt; j += 256) {
            unsigned v = packed[base + j];
            int node = v & 511u;
            int p = offs[node] + atomicAdd(&lcnt[node], 1);
            colv[base + p] = (v >> 9) & 0xFFFFu;
        }
    }
}

// ---------------- segment mean (gather, one wave per node, 8-deep ILP) ----------------
// Neighbor list pre-loaded into registers (lane i holds colv[s0+i], deg<=64 fast path);
// per-edge src broadcast via __shfl; gathers issued in blocks of 8 independent loads.

__global__ __launch_bounds__(256) void agg_mean(const unsigned short* __restrict__ x,
                                                const int* __restrict__ rows,
                                                const int* __restrict__ colv,
                                                unsigned short* __restrict__ nm, int N) {
    int wid = (blockIdx.x * 256 + threadIdx.x) >> 6;
    int lane = threadIdx.x & 63;
    if (wid >= N) return;
    int s0 = rows[wid], s1 = rows[wid + 1];
    int deg = s1 - s0;
    int mn = deg < 64 ? deg : 64;
    int cvec = (lane < mn) ? colv[s0 + lane] : 0;
    float a0 = 0.f, a1 = 0.f;
    int lim = mn - 1;
    for (int j = 0; j < mn; j += 8) {
        unsigned v[8];
        #pragma unroll
        for (int u = 0; u < 8; ++u) {
            int idx = (j + u <= lim) ? (j + u) : lim;   // clamp: dup loads are cache hits
            int s = __shfl(cvec, idx, 64);
            v[u] = *(const unsigned*)(x + (size_t)s * 128 + lane * 2);
        }
        #pragma unroll
        for (int u = 0; u < 8; ++u) {
            if (j + u <= lim) {     // wave-uniform predicate
                a0 += __uint_as_float(v[u] << 16);
                a1 += __uint_as_float(v[u] & 0xffff0000u);
            }
        }
    }
    // rare tail: deg > 64
    for (int e = s0 + 64; e < s1; ++e) {
        int s = colv[e];
        unsigned v_ = *(const unsigned*)(x + (size_t)s * 128 + lane * 2);
        a0 += __uint_as_float(v_ << 16);
        a1 += __uint_as_float(v_ & 0xffff0000u);
    }
    float inv = 1.0f / (float)(deg > 1 ? deg : 1);
    a0 *= inv;
    a1 *= inv;
    unsigned outp = ((unsigned)f2bf(a1) << 16) | (unsigned)f2bf(a0);
    *(unsigned*)(nm + (size_t)wid * 128 + lane * 2) = outp;
}

// ---------------- fused GEMM: out = act(X0*W0^T + [X1*W1^T] + bias) [*exist] ----------------
// Block: 64 nodes x 128 outputs; 4 waves, each 64x32 via 16x16x32 bf16 MFMA.
// LDS rows padded to 136 bf16 (272 B) -> conflict-free ds_read_b128.

__global__ __launch_bounds__(256, 3) void gemm_fused(
    const unsigned short* __restrict__ X0, const unsigned short* __restrict__ X1,
    const unsigned short* __restrict__ W0, const unsigned short* __restrict__ W1,
    const float* __restrict__ bias, const float* __restrict__ ex,
    unsigned short* __restrict__ obf, float* __restrict__ of32,
    int N, int relu, int nphase) {
    __shared__ unsigned short lx[64 * 136];
    __shared__ unsigned short lw[128 * 136];
    int tid = threadIdx.x;
    int lane = tid & 63;
    int w = tid >> 6;
    int node0 = blockIdx.x * 64;
    int n_off = w * 32;
    int q = lane >> 4;      // quad 0..3
    int m16 = lane & 15;

    floatx4 acc[4][2];
    for (int nt = 0; nt < 2; ++nt) {
        float bv = bias[n_off + nt * 16 + m16];
        floatx4 b4 = {bv, bv, bv, bv};
        for (int mt = 0; mt < 4; ++mt) acc[mt][nt] = b4;
    }

    for (int ph = 0; ph < nphase; ++ph) {
        const unsigned short* X = ph ? X1 : X0;
        const unsigned short* W = ph ? W1 : W0;
        // stage X tile (64 x 128)
        for (int i = 0; i < 4; ++i) {
            int c = tid + 256 * i;          // 16B chunk id, 0..1023
            int nd = c >> 4, ck = c & 15;
            short8 v = {0, 0, 0, 0, 0, 0, 0, 0};
            if (node0 + nd < N) v = *(const short8*)(X + (size_t)(node0 + nd) * 128 + ck * 8);
            *(short8*)(lx + nd * 136 + ck * 8) = v;
        }
        // stage W (128 x 128)
        for (int i = 0; i < 8; ++i) {
            int c = tid + 256 * i;          // 0..2047
            int rw = c >> 4, ck = c & 15;
            *(short8*)(lw + rw * 136 + ck * 8) = *(const short8*)(W + rw * 128 + ck * 8);
        }
        __syncthreads();
        for (int kk = 0; kk < 4; ++kk) {
            short8 a[4], b[2];
            for (int mt = 0; mt < 4; ++mt)
                a[mt] = *(const short8*)(lx + (mt * 16 + m16) * 136 + kk * 32 + q * 8);
            for (int nt = 0; nt < 2; ++nt)
                b[nt] = *(const short8*)(lw + (n_off + nt * 16 + m16) * 136 + kk * 32 + q * 8);
            for (int mt = 0; mt < 4; ++mt)
                for (int nt = 0; nt < 2; ++nt)
                    acc[mt][nt] = __builtin_amdgcn_mfma_f32_16x16x32_bf16(a[mt], b[nt], acc[mt][nt], 0, 0, 0);
        }
        __syncthreads();
    }

    // epilogue: C layout col = lane&15, row = q*4 + r
    for (int mt = 0; mt < 4; ++mt) {
        int rbase = node0 + mt * 16 + q * 4;
        for (int r = 0; r < 4; ++r) {
            int rr = rbase + r;
            if (rr >= N) continue;
            float e = ex ? ex[rr] : 1.0f;
            for (int nt = 0; nt < 2; ++nt) {
                float v = acc[mt][nt][r];
                if (relu) v = fmaxf(v, 0.0f);
                v *= e;
                int col = n_off + nt * 16 + m16;
                if (obf) obf[(size_t)rr * 128 + col] = f2bf(v);
                else     of32[(size_t)rr * 128 + col] = v;
            }
        }
    }
}

// ---------------- launch ----------------

extern "C" void kernel_launch(void* const* d_in, const int* in_sizes, int n_in,
                              void* d_out, int out_size, void* d_ws, size_t ws_size,
                              hipStream_t stream) {
    const float* attr = (const float*)d_in[0];
    const float* cc   = (const float*)d_in[1];
    const float* bl   = (const float*)d_in[2];
    const float* ex   = (const float*)d_in[3];
    const float* w_in = (const float*)d_in[4];
    const float* b_in = (const float*)d_in[5];
    const float* w1s  = (const float*)d_in[6];
    const float* b1s  = (const float*)d_in[7];
    const float* w1n  = (const float*)d_in[8];
    const float* b1n  = (const float*)d_in[9];
    const float* w2s  = (const float*)d_in[10];
    const float* b2s  = (const float*)d_in[11];
    const float* w2n  = (const float*)d_in[12];
    const float* b2n  = (const float*)d_in[13];
    const int*   eidx = (const int*)d_in[14];

    int N = in_sizes[3];
    int ATTR = in_sizes[0] / N;
    int E = in_sizes[14] / 2;
    int Npad = ((N + 63) / 64) * 64;
    int nchunk = (N >> 9) + 1;              // node N (for rows[N]) lives in chunk N>>9
    int ntiles = (E + BTILE - 1) / BTILE;

    char* ws = (char*)d_ws;
    size_t off = 0;
    auto alloc = [&](size_t bytes) -> char* {
        off = (off + 255) & ~(size_t)255;
        char* p = ws + off;
        off += bytes;
        return p;
    };
    unsigned short* xa = (unsigned short*)alloc((size_t)Npad * 128 * 2);  // x0, later x2
    unsigned short* xb = (unsigned short*)alloc((size_t)Npad * 128 * 2);  // x1
    unsigned short* xc = (unsigned short*)alloc((size_t)Npad * 128 * 2);  // nm1, later nm2
    int* colv = (int*)alloc((size_t)E * 4);
    unsigned* packed = (unsigned*)alloc((size_t)E * 4);
    int* rows = (int*)alloc((size_t)(N + 256) * 4);
    int* chunk_count  = (int*)alloc(128 * 4);
    int* chunk_base   = (int*)alloc(128 * 4);
    int* chunk_cursor = (int*)alloc(128 * 4);
    unsigned short* wb = (unsigned short*)alloc((size_t)5 * 16384 * 2);
    float* biasf = (float*)alloc(3 * 128 * 4);

    hipMemsetAsync(chunk_count, 0, 128 * 4, stream);

    prep_weights<<<(5 * 16384 + 255) / 256, 256, 0, stream>>>(
        w_in, w1s, w1n, w2s, w2n, b_in, b1s, b1n, b2s, b2n, wb, biasf);
    build_x0<<<(N * 128 + 255) / 256, 256, 0, stream>>>(attr, cc, bl, ex, xa, N, ATTR);

    chunk_hist<<<256, 256, 0, stream>>>(eidx, chunk_count, E);
    chunk_scan<<<1, 128, 0, stream>>>(chunk_count, chunk_base, chunk_cursor);
    bin_pass<<<(ntiles < 256 ? ntiles : 256), 256, 0, stream>>>(eidx, chunk_cursor, packed, E, ntiles);
    chunk_csr<<<nchunk, 256, 0, stream>>>(packed, chunk_base, chunk_cursor, rows, colv, N);

    int gblk = Npad / 64;
    // layer 0: x1 = relu(x0 @ W_in^T + b_in)
    gemm_fused<<<gblk, 256, 0, stream>>>(xa, (const unsigned short*)nullptr,
                                         wb, (const unsigned short*)nullptr,
                                         biasf, (const float*)nullptr,
                                         xb, (float*)nullptr, N, 1, 1);
    // nm1 = segment_mean(x1)
    agg_mean<<<(N + 3) / 4, 256, 0, stream>>>(xb, rows, colv, xc, N);
    // layer 1: x2 = relu(x1 @ W1s^T + nm1 @ W1n^T + b1s + b1n) * exist
    gemm_fused<<<gblk, 256, 0, stream>>>(xb, xc, wb + 16384, wb + 2 * 16384,
                                         biasf + 128, ex, xa, (float*)nullptr, N, 1, 2);
    // nm2 = segment_mean(x2)
    agg_mean<<<(N + 3) / 4, 256, 0, stream>>>(xa, rows, colv, xc, N);
    // layer 2: out = (x2 @ W2s^T + nm2 @ W2n^T + b2s + b2n) * exist   (fp32 out)
    gemm_fused<<<gblk, 256, 0, stream>>>(xa, xc, wb + 3 * 16384, wb + 4 * 16384,
                                         biasf + 256, ex, (unsigned short*)nullptr,
                                         (float*)d_out, N, 0, 2);
}